// Round 18
// baseline (325.168 us; speedup 1.0000x reference)
//
#include <hip/hip_runtime.h>
#include <hip/hip_cooperative_groups.h>
namespace cg = cooperative_groups;

#define N_NODES 10000
#define N_EDGES 160000
#define N_REL 4
#define IN_DIM 15
#define HID 512
#define N_GRAPHS 64
#define NSEG (N_NODES * N_REL)     // 40000
#define K2 (N_REL * HID + HID)     // 2560
#define MAXC 64                    // fixed stride per segment (P(cnt>64) ~ 1e-45)

#define PRE_BLOCKS 512             // 2 blocks/CU guaranteed co-resident
#define PRE_THREADS 256
#define PRE_GT (PRE_BLOCKS * PRE_THREADS)   // 131072

typedef __attribute__((ext_vector_type(8))) short s16x8;
typedef __attribute__((ext_vector_type(4))) short s16x4;
typedef __attribute__((ext_vector_type(4))) float f32x4;

__device__ __forceinline__ float bf2f(short s) {
    return __uint_as_float(((unsigned)(unsigned short)s) << 16);
}
__device__ __forceinline__ short f2bf(float f) {
    unsigned u = __float_as_uint(f);
    u += 0x7fff + ((u >> 16) & 1);          // RNE
    return (short)(u >> 16);
}

// ---------------- workspace byte offsets ----------------
#define B_CNT    0u           // int  [40000]
#define B_ELIST  160000u      // int  [NSEG*64] -> end 10,400,000
#define B_GINV   10400000u    // f32  [64]      -> end 10,400,256
#define B_W1B    10400256u    // bf16 [19][512][4] -> end 10,478,080
#define B_H      10478080u    // bf16 [10000*512] -> end 20,718,080
#define B_MEAN2  20718080u    // bf16 [NSEG*512]  -> end 61,678,080
#define B_BT     61678080u    // bf16 [512][2560] -> end 64,299,520

#define NPB 16
#define L1_JOBS (N_NODES / NPB)          // 625
#define MEAN2_JOBS (NSEG / 4)            // 10000
#define WT_JOBS ((K2 / 64) * (HID / 64)) // 320

// ================= cooperative pre-kernel: zero | bin | layer1 | mean2+wtrans =================
__global__ __launch_bounds__(PRE_THREADS) void pre_kernel(
        const float* __restrict__ x, const int* __restrict__ src,
        const int* __restrict__ tgt, const int* __restrict__ et,
        const int* __restrict__ batch,
        const float* __restrict__ W1_rel, const float* __restrict__ W1_root,
        const float* __restrict__ b1,
        const float* __restrict__ W2_rel, const float* __restrict__ W2_root,
        int* __restrict__ cnts, int* __restrict__ elist,
        float* __restrict__ ginv, short* __restrict__ W1b,
        short* __restrict__ h, short* __restrict__ mean2,
        short* __restrict__ Bt, float* __restrict__ out) {
    cg::grid_group grid = cg::this_grid();
    const int t = threadIdx.x;
    const int bid = blockIdx.x;
    const int gid = bid * PRE_THREADS + t;

    __shared__ float f[NPB][76];          // layer1 staging (4.9 KB)
    __shared__ float tile[64][65];        // wtrans staging (16.6 KB)

    // ---- phase 0: zero cnts/out, ginv, W1->bf16 interleaved ----
    if (gid < NSEG) cnts[gid] = 0;
    if (gid < N_GRAPHS * HID) out[gid] = 0.f;
    if (gid < N_GRAPHS) {
        int g = gid;
        int s, en;
        { int l = 0, hsz = N_NODES;
          while (l < hsz) { int m = (l + hsz) >> 1; if (batch[m] < g) l = m + 1; else hsz = m; }
          s = l; }
        { int l = s, hsz = N_NODES;
          while (l < hsz) { int m = (l + hsz) >> 1; if (batch[m] < g + 1) l = m + 1; else hsz = m; }
          en = l; }
        ginv[g] = (en > s) ? 1.0f / (float)(en - s) : 0.f;
    }
    if (gid < 19 * 512) {
        int gidx = gid >> 9, o = gid & 511;
        short w[4];
        #pragma unroll
        for (int j = 0; j < 4; ++j) {
            int k = gidx * 4 + j;
            float v;
            if (k < 60)      v = W1_rel[(long)k * HID + o];
            else if (k < 75) v = W1_root[(long)(k - 60) * HID + o];
            else             v = 0.f;
            w[j] = f2bf(v);
        }
        *(s16x4*)(W1b + (long)gid * 4) = *(s16x4*)w;
    }
    grid.sync();

    // ---- phase 1: binning ----
    for (int e = gid; e < N_EDGES; e += PRE_GT) {
        int seg = tgt[e] * N_REL + et[e];
        int pos = atomicAdd(&cnts[seg], 1);
        if (pos < MAXC) elist[seg * MAXC + pos] = src[e];
    }
    grid.sync();

    // ---- phase 2: layer1 (fused segment-mean + GEMV, bf16 W1), 2 cols/thread ----
    for (int jb = bid; jb < L1_JOBS; jb += PRE_BLOCKS) {
        const int nb = jb * NPB;
        for (int task = t; task < NPB * 60; task += PRE_THREADS) {
            int m = task / 60, k = task - m * 60;
            int n = nb + m;
            int seg = n * N_REL + k / IN_DIM;
            int d = k % IN_DIM;
            int cnt = cnts[seg]; if (cnt > MAXC) cnt = MAXC;
            int b = seg * MAXC;
            float acc = 0.f;
            for (int i = 0; i < cnt; ++i) acc += x[elist[b + i] * IN_DIM + d];
            f[m][k] = (cnt > 0) ? acc / (float)cnt : 0.f;
        }
        for (int task = t; task < NPB * 16; task += PRE_THREADS) {
            int m = task >> 4, d = task & 15;
            f[m][60 + d] = (d < IN_DIM) ? x[(nb + m) * IN_DIM + d] : 0.f;
        }
        __syncthreads();
        const int o0 = t, o1 = t + 256;
        float acc0[NPB], acc1[NPB];
        const float bias0 = b1[o0], bias1 = b1[o1];
        #pragma unroll
        for (int m = 0; m < NPB; ++m) { acc0[m] = bias0; acc1[m] = bias1; }
        #pragma unroll 2
        for (int k4 = 0; k4 < 76; k4 += 4) {
            s16x4 wv0 = *(const s16x4*)(W1b + (long)((k4 >> 2) * 512 + o0) * 4);
            s16x4 wv1 = *(const s16x4*)(W1b + (long)((k4 >> 2) * 512 + o1) * 4);
            float a0 = bf2f(wv0[0]), a1 = bf2f(wv0[1]), a2 = bf2f(wv0[2]), a3 = bf2f(wv0[3]);
            float c0 = bf2f(wv1[0]), c1 = bf2f(wv1[1]), c2 = bf2f(wv1[2]), c3 = bf2f(wv1[3]);
            #pragma unroll
            for (int m = 0; m < NPB; ++m) {
                float4 fv = *(const float4*)&f[m][k4];
                acc0[m] = fmaf(fv.x, a0, fmaf(fv.y, a1, fmaf(fv.z, a2, fmaf(fv.w, a3, acc0[m]))));
                acc1[m] = fmaf(fv.x, c0, fmaf(fv.y, c1, fmaf(fv.z, c2, fmaf(fv.w, c3, acc1[m]))));
            }
        }
        #pragma unroll
        for (int m = 0; m < NPB; ++m) {
            h[(long)(nb + m) * HID + o0] = f2bf(fmaxf(acc0[m], 0.0f));
            h[(long)(nb + m) * HID + o1] = f2bf(fmaxf(acc1[m], 0.0f));
        }
        __syncthreads();
    }
    grid.sync();

    // ---- phase 3: mean2 (wave/segment) + W2 transpose ----
    for (int j = bid; j < MEAN2_JOBS + WT_JOBS; j += PRE_BLOCKS) {
        if (j < MEAN2_JOBS) {
            const int wid = (j << 2) + (t >> 6);
            const int lane = t & 63;
            int cnt = cnts[wid]; if (cnt > MAXC) cnt = MAXC;
            const int b = wid * MAXC;
            float acc[8] = {0.f,0.f,0.f,0.f,0.f,0.f,0.f,0.f};
            int el = 0;
            if (lane < cnt) el = elist[b + lane];
            for (int i = 0; i < cnt; ++i) {
                int row = __shfl(el, i, 64);
                const s16x8 v = *(const s16x8*)(h + (long)row * HID + lane * 8);
                #pragma unroll
                for (int jj = 0; jj < 8; ++jj) acc[jj] += bf2f(v[jj]);
            }
            const float inv = (cnt > 0) ? 1.0f / (float)cnt : 0.0f;
            s16x8 o;
            #pragma unroll
            for (int jj = 0; jj < 8; ++jj) o[jj] = f2bf(acc[jj] * inv);
            *(s16x8*)(mean2 + (long)wid * HID + lane * 8) = o;
        } else {
            const int bx = j - MEAN2_JOBS;            // 0..319
            const int k0 = (bx % 40) * 64;
            const int o0 = (bx / 40) * 64;
            #pragma unroll
            for (int i = 0; i < 16; ++i) {
                int idx = t + i * 256;
                int kk = idx >> 6, oo = idx & 63;
                int k = k0 + kk;
                float v = (k < N_REL * HID) ? W2_rel[(long)k * HID + o0 + oo]
                                            : W2_root[(long)(k - N_REL * HID) * HID + o0 + oo];
                tile[kk][oo] = v;
            }
            __syncthreads();
            #pragma unroll
            for (int i = 0; i < 16; ++i) {
                int idx = t + i * 256;
                int oo = idx >> 6, kk = idx & 63;
                Bt[(long)(o0 + oo) * K2 + k0 + kk] = f2bf(tile[kk][oo]);
            }
            __syncthreads();
        }
    }
}

// ---------------- layer 2 GEMM: [10000,2560]x[2560,512] bf16 MFMA ----------------
// r11 structure + fused bias+relu+pool epilogue (run-length reduced, ginv-scaled).
#define GM 64
#define GN 128
#define GK 64
#define NT (K2 / GK)                         // 40
#define NWG (4 * ((N_NODES + GM - 1) / GM))  // 628
__global__ __launch_bounds__(256) void gemm2_kernel(
        const short* __restrict__ mean2, const short* __restrict__ h,
        const short* __restrict__ Bt, const float* __restrict__ b2,
        const int* __restrict__ batch, const float* __restrict__ ginv,
        float* __restrict__ out) {
    __shared__ __align__(16) short Al[2][GM * GK];   // 2 x 8 KB
    __shared__ __align__(16) short Bl[2][GN * GK];   // 2 x 16 KB
    const int tid = threadIdx.x;
    const int lane = tid & 63;
    const int w = tid >> 6;
    // XCD-aware bijective remap: each XCD gets a contiguous wgid chunk
    const int orig = blockIdx.x;
    const int q = NWG >> 3, r = NWG & 7;
    const int xcd = orig & 7, cidx = orig >> 3;
    const int wgid = (xcd < r ? xcd * (q + 1) : r * (q + 1) + (xcd - r) * q) + cidx;
    const int m0 = (wgid >> 2) * GM;
    const int n0 = (wgid & 3) * GN;
    const int l15 = lane & 15, lg = lane >> 4;

    f32x4 acc[4][2];
    #pragma unroll
    for (int a = 0; a < 4; ++a)
        #pragma unroll
        for (int bb = 0; bb < 2; ++bb)
            acc[a][bb] = (f32x4){0.f, 0.f, 0.f, 0.f};

#define STAGE(buf, k0)                                                           \
    {                                                                            \
        _Pragma("unroll")                                                        \
        for (int i = 0; i < 2; ++i) {                                            \
            int c = tid + i * 256;                                               \
            int row = c >> 3, slot = c & 7;                                      \
            int srcslot = slot ^ (row & 7);                                      \
            int n = m0 + row; if (n > N_NODES - 1) n = N_NODES - 1;              \
            int kg = (k0) + srcslot * 8;                                         \
            const short* gsrc = (kg < N_REL * HID)                               \
                ? (mean2 + (long)n * (N_REL * HID) + kg)                         \
                : (h + (long)n * HID + (kg - N_REL * HID));                      \
            __builtin_amdgcn_global_load_lds(                                    \
                (const __attribute__((address_space(1))) void*)gsrc,             \
                (__attribute__((address_space(3))) void*)(Al[buf] + c * 8),      \
                16, 0, 0);                                                       \
        }                                                                        \
        _Pragma("unroll")                                                        \
        for (int i = 0; i < 4; ++i) {                                            \
            int c = tid + i * 256;                                               \
            int row = c >> 3, slot = c & 7;                                      \
            int srcslot = slot ^ (row & 7);                                      \
            const short* gsrc = Bt + (long)(n0 + row) * K2 + (k0) + srcslot * 8; \
            __builtin_amdgcn_global_load_lds(                                    \
                (const __attribute__((address_space(1))) void*)gsrc,             \
                (__attribute__((address_space(3))) void*)(Bl[buf] + c * 8),      \
                16, 0, 0);                                                       \
        }                                                                        \
    }

    // prologue
    STAGE(0, 0);
    asm volatile("s_waitcnt vmcnt(0)" ::: "memory");
    __builtin_amdgcn_s_barrier();
    asm volatile("" ::: "memory");

    int cur = 0;
    #pragma unroll 1
    for (int t = 0; t < NT; ++t) {
        if (t + 1 < NT) STAGE(cur ^ 1, (t + 1) * GK);
        #pragma unroll
        for (int hh = 0; hh < 2; ++hh) {
            s16x8 af[4], bfr[2];
            #pragma unroll
            for (int fm = 0; fm < 4; ++fm) {
                int row = fm * 16 + l15;
                int slot = (hh * 4 + lg) ^ (row & 7);
                af[fm] = *(const s16x8*)(Al[cur] + row * GK + slot * 8);
            }
            #pragma unroll
            for (int fn = 0; fn < 2; ++fn) {
                int row = w * 32 + fn * 16 + l15;
                int slot = (hh * 4 + lg) ^ (row & 7);
                bfr[fn] = *(const s16x8*)(Bl[cur] + row * GK + slot * 8);
            }
            #pragma unroll
            for (int fm = 0; fm < 4; ++fm)
                #pragma unroll
                for (int fn = 0; fn < 2; ++fn)
                    asm("v_mfma_f32_16x16x32_bf16 %0, %1, %2, %0"
                        : "+v"(acc[fm][fn]) : "v"(af[fm]), "v"(bfr[fn]));
        }
        asm volatile("s_waitcnt vmcnt(0)" ::: "memory");
        __builtin_amdgcn_s_barrier();
        asm volatile("" ::: "memory");
        cur ^= 1;
    }
#undef STAGE

    // fused epilogue: bias + relu + run-length-reduced, ginv-scaled pooled atomics
    const int col0 = n0 + w * 32 + l15;
    const float bias0 = b2[col0];
    const float bias1 = b2[col0 + 16];
    int cur_g = -1;
    float s0 = 0.f, s1 = 0.f;
    #pragma unroll
    for (int fm = 0; fm < 4; ++fm) {
        #pragma unroll
        for (int r2 = 0; r2 < 4; ++r2) {
            int n = m0 + fm * 16 + 4 * lg + r2;     // ascending within thread
            if (n < N_NODES) {
                int g = batch[n];
                if (g != cur_g) {
                    if (cur_g >= 0) {
                        float gi = ginv[cur_g];
                        float* og = out + (long)cur_g * HID;
                        atomicAdd(og + col0,      s0 * gi);
                        atomicAdd(og + col0 + 16, s1 * gi);
                    }
                    cur_g = g; s0 = 0.f; s1 = 0.f;
                }
                s0 += fmaxf(acc[fm][0][r2] + bias0, 0.f);
                s1 += fmaxf(acc[fm][1][r2] + bias1, 0.f);
            }
        }
    }
    if (cur_g >= 0) {
        float gi = ginv[cur_g];
        float* og = out + (long)cur_g * HID;
        atomicAdd(og + col0,      s0 * gi);
        atomicAdd(og + col0 + 16, s1 * gi);
    }
}

// ---------------- launch ----------------
extern "C" void kernel_launch(void* const* d_in, const int* in_sizes, int n_in,
                              void* d_out, int out_size, void* d_ws, size_t ws_size,
                              hipStream_t stream) {
    const float* x       = (const float*)d_in[0];
    const int*   ei      = (const int*)d_in[1];
    const int*   src     = ei;
    const int*   tgt     = ei + N_EDGES;
    const int*   etype   = (const int*)d_in[2];
    const int*   batch   = (const int*)d_in[3];
    const float* W1_rel  = (const float*)d_in[4];
    const float* W1_root = (const float*)d_in[5];
    const float* b1      = (const float*)d_in[6];
    const float* W2_rel  = (const float*)d_in[7];
    const float* W2_root = (const float*)d_in[8];
    const float* b2      = (const float*)d_in[9];
    float* out = (float*)d_out;

    char* ws = (char*)d_ws;
    int*   cnts  = (int*)(ws + B_CNT);
    int*   elist = (int*)(ws + B_ELIST);
    float* ginv  = (float*)(ws + B_GINV);
    short* W1b   = (short*)(ws + B_W1B);
    short* h     = (short*)(ws + B_H);
    short* mean2 = (short*)(ws + B_MEAN2);
    short* Bt    = (short*)(ws + B_BT);

    void* kargs[] = {
        (void*)&x, (void*)&src, (void*)&tgt, (void*)&etype, (void*)&batch,
        (void*)&W1_rel, (void*)&W1_root, (void*)&b1, (void*)&W2_rel, (void*)&W2_root,
        (void*)&cnts, (void*)&elist, (void*)&ginv, (void*)&W1b,
        (void*)&h, (void*)&mean2, (void*)&Bt, (void*)&out
    };
    hipLaunchCooperativeKernel((void*)pre_kernel, dim3(PRE_BLOCKS), dim3(PRE_THREADS),
                               kargs, 0, stream);

    gemm2_kernel<<<NWG, 256, 0, stream>>>(mean2, h, Bt, b2, batch, ginv, out);
}

// Round 19
// 122.167 us; speedup vs baseline: 2.6617x; 2.6617x over previous
//
#include <hip/hip_runtime.h>

#define N_NODES 10000
#define N_EDGES 160000
#define N_REL 4
#define IN_DIM 15
#define HID 512
#define N_GRAPHS 64
#define NSEG (N_NODES * N_REL)     // 40000
#define K2 (N_REL * HID + HID)     // 2560
#define MAXC 64                    // fixed stride per segment (P(cnt>64) ~ 1e-45)

typedef __attribute__((ext_vector_type(8))) short s16x8;
typedef __attribute__((ext_vector_type(4))) short s16x4;
typedef __attribute__((ext_vector_type(4))) float f32x4;

__device__ __forceinline__ float bf2f(short s) {
    return __uint_as_float(((unsigned)(unsigned short)s) << 16);
}
__device__ __forceinline__ short f2bf(float f) {
    unsigned u = __float_as_uint(f);
    u += 0x7fff + ((u >> 16) & 1);          // RNE
    return (short)(u >> 16);
}

// ---------------- workspace byte offsets ----------------
#define B_CNT    0u           // int  [40000]
#define B_ELIST  160000u      // int  [NSEG*64] -> end 10,400,000
#define B_GINV   10400000u    // f32  [64]      -> end 10,400,256
#define B_W1B    10400256u    // bf16 [19][512][4] -> end 10,478,080
#define B_H      10478080u    // bf16 [10000*512] -> end 20,718,080
#define B_MEAN2  20718080u    // bf16 [NSEG*512]  -> end 61,678,080
#define B_BT     61678080u    // bf16 [512][2560] -> end 64,299,520

#define BIN_BLOCKS 625                      // covers N_EDGES with 256 thr
#define WT_JOBS ((K2 / 64) * (HID / 64))    // 320

// ---------------- binning + out-zero + ginv + W1->bf16 + W2 transpose ----------------
__global__ __launch_bounds__(256) void bin_kernel(
        const int* __restrict__ src, const int* __restrict__ tgt,
        const int* __restrict__ et, const int* __restrict__ batch,
        const float* __restrict__ W1_rel, const float* __restrict__ W1_root,
        const float* __restrict__ W2_rel, const float* __restrict__ W2_root,
        int* __restrict__ cnt, int* __restrict__ elist,
        float* __restrict__ out, float* __restrict__ ginv,
        short* __restrict__ W1b, short* __restrict__ Bt) {
    __shared__ float tile[64][65];
    if (blockIdx.x >= BIN_BLOCKS) {
        // W2cat transpose -> Bt[o][k] bf16 (independent of binning)
        const int bx = blockIdx.x - BIN_BLOCKS;   // 0..319
        const int k0 = (bx % 40) * 64;
        const int o0 = (bx / 40) * 64;
        const int t = threadIdx.x;
        #pragma unroll
        for (int i = 0; i < 16; ++i) {
            int idx = t + i * 256;
            int kk = idx >> 6, oo = idx & 63;
            int k = k0 + kk;
            float v = (k < N_REL * HID) ? W2_rel[(long)k * HID + o0 + oo]
                                        : W2_root[(long)(k - N_REL * HID) * HID + o0 + oo];
            tile[kk][oo] = v;
        }
        __syncthreads();
        #pragma unroll
        for (int i = 0; i < 16; ++i) {
            int idx = t + i * 256;
            int oo = idx >> 6, kk = idx & 63;
            Bt[(long)(o0 + oo) * K2 + k0 + kk] = f2bf(tile[kk][oo]);
        }
        return;
    }
    int e = blockIdx.x * blockDim.x + threadIdx.x;
    if (e < N_GRAPHS * HID) out[e] = 0.f;
    // ginv[g] = 1/graph node count (batch sorted)
    if (e < N_GRAPHS) {
        int g = e;
        int s, en;
        { int l = 0, hsz = N_NODES;
          while (l < hsz) { int m = (l + hsz) >> 1; if (batch[m] < g) l = m + 1; else hsz = m; }
          s = l; }
        { int l = s, hsz = N_NODES;
          while (l < hsz) { int m = (l + hsz) >> 1; if (batch[m] < g + 1) l = m + 1; else hsz = m; }
          en = l; }
        ginv[g] = (en > s) ? 1.0f / (float)(en - s) : 0.f;
    }
    // W1cat -> bf16 interleaved [k4-group][o][4]
    if (e < 19 * 512) {
        int gidx = e >> 9, o = e & 511;
        short w[4];
        #pragma unroll
        for (int j = 0; j < 4; ++j) {
            int k = gidx * 4 + j;
            float v;
            if (k < 60)      v = W1_rel[(long)k * HID + o];
            else if (k < 75) v = W1_root[(long)(k - 60) * HID + o];
            else             v = 0.f;
            w[j] = f2bf(v);
        }
        *(s16x4*)(W1b + (long)e * 4) = *(s16x4*)w;
    }
    if (e >= N_EDGES) return;
    int seg = tgt[e] * N_REL + et[e];
    int pos = atomicAdd(&cnt[seg], 1);
    if (pos < MAXC) elist[seg * MAXC + pos] = src[e];
}

// ---------------- layer 1 (fused segment-mean + GEMV, bf16 W1) ----------------
#define NPB 16
__global__ __launch_bounds__(512) void layer1_kernel(
        const float* __restrict__ x, const int* __restrict__ cnts,
        const int* __restrict__ elist, const short* __restrict__ W1b,
        const float* __restrict__ b1, short* __restrict__ h) {
    const int nb = blockIdx.x * NPB;                  // 625 blocks, no tail
    __shared__ float f[NPB][76];                      // f[.][75] = 0 pad
    const int t = threadIdx.x;
    // rel-mean part: 960 tasks (m, k<60)
    for (int task = t; task < NPB * 60; task += 512) {
        int m = task / 60, k = task - m * 60;
        int n = nb + m;
        int seg = n * N_REL + k / IN_DIM;
        int d = k % IN_DIM;
        int cnt = cnts[seg]; if (cnt > MAXC) cnt = MAXC;
        int b = seg * MAXC;
        float acc = 0.f;
        for (int i = 0; i < cnt; ++i) acc += x[elist[b + i] * IN_DIM + d];
        f[m][k] = (cnt > 0) ? acc / (float)cnt : 0.f;
    }
    // root-x part + pad: 256 tasks
    for (int task = t; task < NPB * 16; task += 512) {
        int m = task >> 4, d = task & 15;
        f[m][60 + d] = (d < IN_DIM) ? x[(nb + m) * IN_DIM + d] : 0.f;
    }
    __syncthreads();
    const int o = t;
    float acc[NPB];
    const float bias = b1[o];
    #pragma unroll
    for (int m = 0; m < NPB; ++m) acc[m] = bias;
    #pragma unroll 2
    for (int k4 = 0; k4 < 76; k4 += 4) {
        s16x4 wv = *(const s16x4*)(W1b + (long)((k4 >> 2) * 512 + o) * 4);
        float w0 = bf2f(wv[0]), w1 = bf2f(wv[1]), w2 = bf2f(wv[2]), w3 = bf2f(wv[3]);
        #pragma unroll
        for (int m = 0; m < NPB; ++m) {
            float4 fv = *(const float4*)&f[m][k4];
            acc[m] = fmaf(fv.x, w0, fmaf(fv.y, w1, fmaf(fv.z, w2, fmaf(fv.w, w3, acc[m]))));
        }
    }
    #pragma unroll
    for (int m = 0; m < NPB; ++m)
        h[(long)(nb + m) * HID + o] = f2bf(fmaxf(acc[m], 0.0f));
}

// ---------------- layer-2 aggregation: wave/segment ----------------
#define MEAN2_BLOCKS (NSEG / 4)    // 10000
__global__ __launch_bounds__(256) void mean2_kernel(
        const short* __restrict__ h, const int* __restrict__ cnts,
        const int* __restrict__ elist, short* __restrict__ mean2) {
    const int wid = (blockIdx.x << 2) + (threadIdx.x >> 6);
    const int lane = threadIdx.x & 63;
    int cnt = cnts[wid]; if (cnt > MAXC) cnt = MAXC;
    const int b = wid * MAXC;
    float acc[8] = {0.f,0.f,0.f,0.f,0.f,0.f,0.f,0.f};
    int el = 0;
    if (lane < cnt) el = elist[b + lane];
    for (int i = 0; i < cnt; ++i) {
        int row = __shfl(el, i, 64);
        const s16x8 v = *(const s16x8*)(h + (long)row * HID + lane * 8);
        #pragma unroll
        for (int j = 0; j < 8; ++j) acc[j] += bf2f(v[j]);
    }
    const float inv = (cnt > 0) ? 1.0f / (float)cnt : 0.0f;
    s16x8 o;
    #pragma unroll
    for (int j = 0; j < 8; ++j) o[j] = f2bf(acc[j] * inv);
    *(s16x8*)(mean2 + (long)wid * HID + lane * 8) = o;
}

// ---------------- layer 2 GEMM: [10000,2560]x[2560,512] bf16 MFMA ----------------
// r11 structure + fused bias+relu+pool epilogue (run-length reduced, ginv-scaled).
#define GM 64
#define GN 128
#define GK 64
#define NT (K2 / GK)                         // 40
#define NWG (4 * ((N_NODES + GM - 1) / GM))  // 628
__global__ __launch_bounds__(256) void gemm2_kernel(
        const short* __restrict__ mean2, const short* __restrict__ h,
        const short* __restrict__ Bt, const float* __restrict__ b2,
        const int* __restrict__ batch, const float* __restrict__ ginv,
        float* __restrict__ out) {
    __shared__ __align__(16) short Al[2][GM * GK];   // 2 x 8 KB
    __shared__ __align__(16) short Bl[2][GN * GK];   // 2 x 16 KB
    const int tid = threadIdx.x;
    const int lane = tid & 63;
    const int w = tid >> 6;
    // XCD-aware bijective remap: each XCD gets a contiguous wgid chunk
    const int orig = blockIdx.x;
    const int q = NWG >> 3, r = NWG & 7;
    const int xcd = orig & 7, cidx = orig >> 3;
    const int wgid = (xcd < r ? xcd * (q + 1) : r * (q + 1) + (xcd - r) * q) + cidx;
    const int m0 = (wgid >> 2) * GM;
    const int n0 = (wgid & 3) * GN;
    const int l15 = lane & 15, lg = lane >> 4;

    f32x4 acc[4][2];
    #pragma unroll
    for (int a = 0; a < 4; ++a)
        #pragma unroll
        for (int bb = 0; bb < 2; ++bb)
            acc[a][bb] = (f32x4){0.f, 0.f, 0.f, 0.f};

#define STAGE(buf, k0)                                                           \
    {                                                                            \
        _Pragma("unroll")                                                        \
        for (int i = 0; i < 2; ++i) {                                            \
            int c = tid + i * 256;                                               \
            int row = c >> 3, slot = c & 7;                                      \
            int srcslot = slot ^ (row & 7);                                      \
            int n = m0 + row; if (n > N_NODES - 1) n = N_NODES - 1;              \
            int kg = (k0) + srcslot * 8;                                         \
            const short* gsrc = (kg < N_REL * HID)                               \
                ? (mean2 + (long)n * (N_REL * HID) + kg)                         \
                : (h + (long)n * HID + (kg - N_REL * HID));                      \
            __builtin_amdgcn_global_load_lds(                                    \
                (const __attribute__((address_space(1))) void*)gsrc,             \
                (__attribute__((address_space(3))) void*)(Al[buf] + c * 8),      \
                16, 0, 0);                                                       \
        }                                                                        \
        _Pragma("unroll")                                                        \
        for (int i = 0; i < 4; ++i) {                                            \
            int c = tid + i * 256;                                               \
            int row = c >> 3, slot = c & 7;                                      \
            int srcslot = slot ^ (row & 7);                                      \
            const short* gsrc = Bt + (long)(n0 + row) * K2 + (k0) + srcslot * 8; \
            __builtin_amdgcn_global_load_lds(                                    \
                (const __attribute__((address_space(1))) void*)gsrc,             \
                (__attribute__((address_space(3))) void*)(Bl[buf] + c * 8),      \
                16, 0, 0);                                                       \
        }                                                                        \
    }

    // prologue
    STAGE(0, 0);
    asm volatile("s_waitcnt vmcnt(0)" ::: "memory");
    __builtin_amdgcn_s_barrier();
    asm volatile("" ::: "memory");

    int cur = 0;
    #pragma unroll 1
    for (int t = 0; t < NT; ++t) {
        if (t + 1 < NT) STAGE(cur ^ 1, (t + 1) * GK);
        #pragma unroll
        for (int hh = 0; hh < 2; ++hh) {
            s16x8 af[4], bfr[2];
            #pragma unroll
            for (int fm = 0; fm < 4; ++fm) {
                int row = fm * 16 + l15;
                int slot = (hh * 4 + lg) ^ (row & 7);
                af[fm] = *(const s16x8*)(Al[cur] + row * GK + slot * 8);
            }
            #pragma unroll
            for (int fn = 0; fn < 2; ++fn) {
                int row = w * 32 + fn * 16 + l15;
                int slot = (hh * 4 + lg) ^ (row & 7);
                bfr[fn] = *(const s16x8*)(Bl[cur] + row * GK + slot * 8);
            }
            #pragma unroll
            for (int fm = 0; fm < 4; ++fm)
                #pragma unroll
                for (int fn = 0; fn < 2; ++fn)
                    asm("v_mfma_f32_16x16x32_bf16 %0, %1, %2, %0"
                        : "+v"(acc[fm][fn]) : "v"(af[fm]), "v"(bfr[fn]));
        }
        asm volatile("s_waitcnt vmcnt(0)" ::: "memory");
        __builtin_amdgcn_s_barrier();
        asm volatile("" ::: "memory");
        cur ^= 1;
    }
#undef STAGE

    // fused epilogue: bias + relu + run-length-reduced, ginv-scaled pooled atomics
    const int col0 = n0 + w * 32 + l15;
    const float bias0 = b2[col0];
    const float bias1 = b2[col0 + 16];
    int cur_g = -1;
    float s0 = 0.f, s1 = 0.f;
    #pragma unroll
    for (int fm = 0; fm < 4; ++fm) {
        #pragma unroll
        for (int r2 = 0; r2 < 4; ++r2) {
            int n = m0 + fm * 16 + 4 * lg + r2;     // ascending within thread
            if (n < N_NODES) {
                int g = batch[n];
                if (g != cur_g) {
                    if (cur_g >= 0) {
                        float gi = ginv[cur_g];
                        float* og = out + (long)cur_g * HID;
                        atomicAdd(og + col0,      s0 * gi);
                        atomicAdd(og + col0 + 16, s1 * gi);
                    }
                    cur_g = g; s0 = 0.f; s1 = 0.f;
                }
                s0 += fmaxf(acc[fm][0][r2] + bias0, 0.f);
                s1 += fmaxf(acc[fm][1][r2] + bias1, 0.f);
            }
        }
    }
    if (cur_g >= 0) {
        float gi = ginv[cur_g];
        float* og = out + (long)cur_g * HID;
        atomicAdd(og + col0,      s0 * gi);
        atomicAdd(og + col0 + 16, s1 * gi);
    }
}

// ---------------- launch ----------------
extern "C" void kernel_launch(void* const* d_in, const int* in_sizes, int n_in,
                              void* d_out, int out_size, void* d_ws, size_t ws_size,
                              hipStream_t stream) {
    const float* x       = (const float*)d_in[0];
    const int*   ei      = (const int*)d_in[1];
    const int*   src     = ei;
    const int*   tgt     = ei + N_EDGES;
    const int*   etype   = (const int*)d_in[2];
    const int*   batch   = (const int*)d_in[3];
    const float* W1_rel  = (const float*)d_in[4];
    const float* W1_root = (const float*)d_in[5];
    const float* b1      = (const float*)d_in[6];
    const float* W2_rel  = (const float*)d_in[7];
    const float* W2_root = (const float*)d_in[8];
    const float* b2      = (const float*)d_in[9];
    float* out = (float*)d_out;

    char* ws = (char*)d_ws;
    int*   cnts  = (int*)(ws + B_CNT);
    int*   elist = (int*)(ws + B_ELIST);
    float* ginv  = (float*)(ws + B_GINV);
    short* W1b   = (short*)(ws + B_W1B);
    short* h     = (short*)(ws + B_H);
    short* mean2 = (short*)(ws + B_MEAN2);
    short* Bt    = (short*)(ws + B_BT);

    hipMemsetAsync(cnts, 0, NSEG * sizeof(int), stream);

    bin_kernel<<<BIN_BLOCKS + WT_JOBS, 256, 0, stream>>>(
        src, tgt, etype, batch, W1_rel, W1_root, W2_rel, W2_root,
        cnts, elist, out, ginv, W1b, Bt);

    layer1_kernel<<<N_NODES / NPB, 512, 0, stream>>>(x, cnts, elist, W1b, b1, h);

    mean2_kernel<<<MEAN2_BLOCKS, 256, 0, stream>>>(h, cnts, elist, mean2);

    gemm2_kernel<<<NWG, 256, 0, stream>>>(mean2, h, Bt, b2, batch, ginv, out);
}